// Round 1
// baseline (6000.232 us; speedup 1.0000x reference)
//
#include <hip/hip_runtime.h>
#include <math.h>

#define INF_ 1e10f

static constexpr int B_  = 64;
static constexpr int N_  = 197;
static constexpr int C_  = 768;
static constexpr int H_  = 12;
static constexpr int T_  = 196;   // N-1 tokens clustered
static constexpr int KC_ = 98;    // NUM_CLUSTERS
static constexpr int KT_ = 99;    // NUM_CLUSTERS + 1
static constexpr int HF_ = 3072;

__device__ __forceinline__ float wave_sum(float v){
#pragma unroll
  for(int o=32;o;o>>=1) v += __shfl_down(v,o);
  return v;
}

// ---------------- LayerNorm (row = 768, block = 256) ----------------
__global__ __launch_bounds__(256) void ln_kernel(const float* __restrict__ in,
    const float* __restrict__ g, const float* __restrict__ bb,
    float* __restrict__ out){
  int row = blockIdx.x;
  const float* xr = in + (size_t)row*C_;
  int tid = threadIdx.x;
  float v0=xr[tid], v1=xr[tid+256], v2=xr[tid+512];
  __shared__ float sred[4];
  __shared__ float smean, svar;
  float s = wave_sum(v0+v1+v2);
  int w=tid>>6, l=tid&63;
  if(l==0) sred[w]=s;
  __syncthreads();
  if(tid==0) smean = (sred[0]+sred[1]+sred[2]+sred[3])/(float)C_;
  __syncthreads();
  float m = smean;
  float d0=v0-m, d1=v1-m, d2=v2-m;
  float q = wave_sum(d0*d0+d1*d1+d2*d2);
  if(l==0) sred[w]=q;
  __syncthreads();
  if(tid==0) svar = (sred[0]+sred[1]+sred[2]+sred[3])/(float)C_;
  __syncthreads();
  float sq = sqrtf(svar + 1e-5f);
  float* orow = out + (size_t)row*C_;
  orow[tid]     = d0/sq*g[tid]     + bb[tid];
  orow[tid+256] = d1/sq*g[tid+256] + bb[tid+256];
  orow[tid+512] = d2/sq*g[tid+512] + bb[tid+512];
}

// ---------------- f32 tiled GEMM: C = A[MxK] @ B[KxN] (+epilogue) ----------------
// EPI: 0 = store, 1/3 = +res +bias, 2 = +bias then exact GELU
template<int EPI>
__global__ __launch_bounds__(256) void gemm_f32(const float* __restrict__ A,
    const float* __restrict__ Bw, const float* __restrict__ bias,
    const float* __restrict__ res, float* __restrict__ Cmat,
    int M, int N, int K){
  constexpr int BM=64, BN=64, BK=32;
  __shared__ float As[BK][BM+4];
  __shared__ float Bs[BK][BN+4];
  int bn = blockIdx.x*BN, bm = blockIdx.y*BM;
  int tid = threadIdx.x;
  int tm = (tid>>4)*4, tn = (tid&15)*4;
  float acc[4][4] = {};
  for(int k0=0;k0<K;k0+=BK){
#pragma unroll
    for(int t=tid;t<BM*BK;t+=256){
      int m=t>>5, kk=t&31;
      As[kk][m] = A[(size_t)(bm+m)*K + k0+kk];
    }
#pragma unroll
    for(int t=tid;t<BK*BN;t+=256){
      int kk=t>>6, n=t&63;
      Bs[kk][n] = Bw[(size_t)(k0+kk)*N + bn+n];
    }
    __syncthreads();
#pragma unroll
    for(int kk=0;kk<BK;kk++){
      float4 a4 = *reinterpret_cast<const float4*>(&As[kk][tm]);
      float4 b4 = *reinterpret_cast<const float4*>(&Bs[kk][tn]);
      float av[4]={a4.x,a4.y,a4.z,a4.w}, bv[4]={b4.x,b4.y,b4.z,b4.w};
#pragma unroll
      for(int i=0;i<4;i++)
#pragma unroll
        for(int j=0;j<4;j++) acc[i][j] += av[i]*bv[j];
    }
    __syncthreads();
  }
#pragma unroll
  for(int i=0;i<4;i++){
    int m = bm+tm+i;
#pragma unroll
    for(int j=0;j<4;j++){
      int n = bn+tn+j;
      float v = acc[i][j];
      size_t idx = (size_t)m*N + n;
      if constexpr(EPI==1 || EPI==3) v = (res[idx] + v) + bias[n];
      if constexpr(EPI==2){ v += bias[n]; v = 0.5f*v*(1.0f+erff(v*0.70710678118654752f)); }
      Cmat[idx] = v;
    }
  }
}

// ---------------- metric = mean over heads of K, then L2-normalize ----------------
__global__ __launch_bounds__(64) void metric_kernel(const float* __restrict__ qkv,
    float* __restrict__ mnorm){
  int n = blockIdx.x, b = blockIdx.y, d = threadIdx.x;
  const float* base = qkv + ((size_t)(b*N_+n))*(3*C_) + C_ + d;  // k part
  float m=0;
#pragma unroll
  for(int h=0;h<H_;h++) m += base[h*64];
  m = m / 12.0f;
  float q = m*m;
#pragma unroll
  for(int o=32;o;o>>=1) q += __shfl_xor(q,o);
  float norm = sqrtf(q);
  if(n>=1) mnorm[((size_t)b*T_ + (n-1))*64 + d] = m/norm;   // drop cls token
}

// ---------------- attention: one block per (b,h); K,V staged in LDS ----------------
__global__ __launch_bounds__(256) void attn_kernel(const float* __restrict__ qkv,
    const float* __restrict__ attn_size, float* __restrict__ xa){
  int h = blockIdx.x, b = blockIdx.y;
  __shared__ float Ks[N_][65];
  __shared__ float Vs[N_][65];
  __shared__ float lsz[N_];
  __shared__ float qs[4][64];
  __shared__ float sw[4][200];
  int tid = threadIdx.x;
  for(int t=tid;t<N_*64;t+=256){
    int n=t>>6, d=t&63;
    size_t rb = ((size_t)(b*N_+n))*(3*C_) + h*64 + d;
    Ks[n][d] = qkv[rb + C_];
    Vs[n][d] = qkv[rb + 2*C_];
  }
  for(int t=tid;t<N_;t+=256) lsz[t] = logf(attn_size[b*N_+t]);
  __syncthreads();
  int w=tid>>6, l=tid&63;
  for(int r=w;r<N_;r+=4){
    qs[w][l] = qkv[((size_t)(b*N_+r))*(3*C_) + h*64 + l];
    asm volatile("s_waitcnt lgkmcnt(0)" ::: "memory");  // wave-internal LDS visibility
    float sc[4]; float smax=-INFINITY;
#pragma unroll
    for(int s=0;s<4;s++){
      int k = l + 64*s;
      float a = -INFINITY;
      if(k<N_){
        float accq=0.0f;
        for(int d=0;d<64;d++) accq += qs[w][d]*Ks[k][d];
        a = accq*0.125f + lsz[k];     // hd^-0.5 = 0.125; + log(size)
        smax = fmaxf(smax, a);
      }
      sc[s]=a;
    }
#pragma unroll
    for(int o=32;o;o>>=1) smax = fmaxf(smax, __shfl_xor(smax,o));
    float lsum=0.0f;
#pragma unroll
    for(int s=0;s<4;s++){
      int k = l + 64*s;
      if(k<N_){ float p = expf(sc[s]-smax); sw[w][k]=p; lsum+=p; }
    }
#pragma unroll
    for(int o=32;o;o>>=1) lsum += __shfl_xor(lsum,o);
    asm volatile("s_waitcnt lgkmcnt(0)" ::: "memory");
    float acc=0.0f;
    for(int k=0;k<N_;k++) acc += sw[w][k]*Vs[k][l];
    xa[((size_t)(b*N_+r))*C_ + h*64 + l] = acc/lsum;
  }
}

// ---------------- agglomerative clustering: one block per batch, D in LDS ----------------
__global__ __launch_bounds__(256) void cluster_kernel(const float* __restrict__ mnorm,
    int* __restrict__ labs_ws, float* __restrict__ labs_out){
  int b = blockIdx.x;
  __shared__ float D[T_][T_+1];          // 154,448 B
  __shared__ float sizes[T_];
  __shared__ int   labels[T_];
  __shared__ int   active[T_];
  __shared__ int   rank_[T_];
  __shared__ float rbv[4];
  __shared__ int   rbi[4];
  __shared__ int   sij[2];
  __shared__ float snn[2];
  int tid = threadIdx.x;
  const float* mb = mnorm + (size_t)b*T_*64;

  for(int t=tid;t<T_*T_;t+=256){
    int r=t/T_, c=t%T_;
    float dot=0.0f;
    for(int d=0;d<64;d++) dot += mb[r*64+d]*mb[c*64+d];
    D[r][c] = (r==c) ? INF_ : (1.0f - dot);
  }
  for(int t=tid;t<T_;t+=256){ sizes[t]=1.0f; labels[t]=t; active[t]=1; }
  __syncthreads();

  for(int it=0; it<T_-KC_; it++){
    // masked flat argmin, first-index tie-break (row-major like jnp.argmin)
    float bv=INF_; int bi=0x7fffffff;
    for(int t=tid;t<T_*T_;t+=256){
      int r=t/T_, c=t%T_;
      if(active[r] & active[c]){
        float v = D[r][c];
        if(v < bv){ bv=v; bi=t; }
      }
    }
#pragma unroll
    for(int o=32;o;o>>=1){
      float ov=__shfl_down(bv,o); int oi=__shfl_down(bi,o);
      if(ov<bv || (ov==bv && oi<bi)){ bv=ov; bi=oi; }
    }
    int w=tid>>6, l=tid&63;
    if(l==0){ rbv[w]=bv; rbi[w]=bi; }
    __syncthreads();
    if(tid==0){
      bv=rbv[0]; bi=rbi[0];
      for(int u=1;u<4;u++) if(rbv[u]<bv || (rbv[u]==bv && rbi[u]<bi)){ bv=rbv[u]; bi=rbi[u]; }
      int i0=bi/T_, j0=bi%T_;
      int i=min(i0,j0), j=max(i0,j0);
      sij[0]=i; sij[1]=j; snn[0]=sizes[i]; snn[1]=sizes[j];
    }
    __syncthreads();
    int i=sij[0], j=sij[1]; float ni=snn[0], nj=snn[1];
    float nd=0.0f;
    int k=tid;
    if(k<T_) nd = (ni*D[i][k] + nj*D[j][k]) / (ni+nj);   // Lance-Williams avg linkage
    __syncthreads();
    if(k<T_){
      float v = (k==i || k==j) ? INF_ : nd;
      D[i][k]=v; D[k][i]=v;
      D[j][k]=INF_; D[k][j]=INF_;
      if(labels[k]==j) labels[k]=i;
    }
    if(tid==0){ sizes[i]=ni+nj; active[j]=0; }
    __syncthreads();
  }

  if(tid==0){
    int c=0;
    for(int t=0;t<T_;t++){ c += active[t]; rank_[t]=c-1; }
    labs_ws[b*N_]=0; labs_out[b*N_]=0.0f;
  }
  __syncthreads();
  for(int t=tid;t<T_;t+=256){
    int lab = rank_[labels[t]] + 1;
    labs_ws[b*N_+1+t] = lab;
    labs_out[b*N_+1+t] = (float)lab;
  }
}

// ---------------- weighted-average merge: one block per (k,b) ----------------
__global__ __launch_bounds__(256) void merge_kernel(const float* __restrict__ x1,
    const float* __restrict__ asz, const int* __restrict__ labs,
    float* __restrict__ x2, float* __restrict__ size_out){
  int k = blockIdx.x, b = blockIdx.y;
  __shared__ int   lab[N_];
  __shared__ float sz[N_];
  __shared__ float ssum_s;
  int tid = threadIdx.x;
  for(int t=tid;t<N_;t+=256){ lab[t]=labs[b*N_+t]; sz[t]=asz[b*N_+t]; }
  __syncthreads();
  if(tid==0){
    float s=0.0f;
    for(int n=0;n<N_;n++) if(lab[n]==k) s += sz[n];
    ssum_s = s;
  }
  __syncthreads();
  float ssum = ssum_s;
  for(int c=tid;c<C_;c+=256){
    float acc=0.0f;
    for(int n=0;n<N_;n++) if(lab[n]==k) acc += x1[((size_t)(b*N_+n))*C_+c]*sz[n];
    x2[((size_t)(b*KT_+k))*C_+c] = acc/ssum;
  }
  if(tid==0) size_out[b*KT_+k] = ssum;
}

extern "C" void kernel_launch(void* const* d_in, const int* in_sizes, int n_in,
                              void* d_out, int out_size, void* d_ws, size_t ws_size,
                              hipStream_t stream){
  const float* x      = (const float*)d_in[0];
  const float* asz    = (const float*)d_in[1];
  const float* n1_g   = (const float*)d_in[2];
  const float* n1_b   = (const float*)d_in[3];
  const float* w_qkv  = (const float*)d_in[4];
  const float* w_proj = (const float*)d_in[5];
  const float* b_proj = (const float*)d_in[6];
  const float* n2_g   = (const float*)d_in[7];
  const float* n2_b   = (const float*)d_in[8];
  const float* w_fc1  = (const float*)d_in[9];
  const float* b_fc1  = (const float*)d_in[10];
  const float* w_fc2  = (const float*)d_in[11];
  const float* b_fc2  = (const float*)d_in[12];

  const size_t ROWS = (size_t)B_*N_;   // 12608
  float* ws   = (float*)d_ws;
  float* h    = ws;                                // [ROWS*C]   LN1 out, later x1
  float* qkv  = h + ROWS*C_;                       // [ROWS*3C]
  float* x2   = qkv;                               // reuse after qkv dead
  float* h2   = x2 + (size_t)B_*KT_*C_;            // LN2 out
  float* h3   = h2 + (size_t)B_*KT_*C_;            // fc1 out (spills into dead mnorm)
  float* mnorm= qkv + ROWS*3*C_;                   // [B*T*64]
  float* xa   = mnorm + (size_t)B_*T_*64;          // [ROWS*C]
  float* x1   = h;                                 // proj out (h dead by then)
  int*   labs = (int*)(xa + ROWS*C_);              // [B*N]

  float* out     = (float*)d_out;
  float* out_sz  = out + (size_t)B_*KT_*C_;
  float* out_lab = out_sz + (size_t)B_*KT_;

  ln_kernel<<<dim3((unsigned)ROWS),256,0,stream>>>(x, n1_g, n1_b, h);
  gemm_f32<0><<<dim3(36,197),256,0,stream>>>(h, w_qkv, nullptr, nullptr, qkv, 12608, 3*C_, C_);
  metric_kernel<<<dim3(N_,B_),64,0,stream>>>(qkv, mnorm);
  attn_kernel<<<dim3(H_,B_),256,0,stream>>>(qkv, asz, xa);
  gemm_f32<1><<<dim3(12,197),256,0,stream>>>(xa, w_proj, b_proj, x, x1, 12608, C_, C_);
  cluster_kernel<<<dim3(B_),256,0,stream>>>(mnorm, labs, out_lab);
  merge_kernel<<<dim3(KT_,B_),256,0,stream>>>(x1, asz, labs, x2, out_sz);
  ln_kernel<<<dim3((unsigned)(B_*KT_)),256,0,stream>>>(x2, n2_g, n2_b, h2);
  gemm_f32<2><<<dim3(48,99),256,0,stream>>>(h2, w_fc1, b_fc1, nullptr, h3, B_*KT_, HF_, C_);
  gemm_f32<3><<<dim3(12,99),256,0,stream>>>(h3, w_fc2, b_fc2, x2, out, B_*KT_, C_, HF_);
}

// Round 2
// 5411.325 us; speedup vs baseline: 1.1088x; 1.1088x over previous
//
#include <hip/hip_runtime.h>
#include <math.h>

#define INF_ 1e10f

static constexpr int B_  = 64;
static constexpr int N_  = 197;
static constexpr int C_  = 768;
static constexpr int H_  = 12;
static constexpr int T_  = 196;   // N-1 tokens clustered
static constexpr int KC_ = 98;    // NUM_CLUSTERS
static constexpr int KT_ = 99;    // NUM_CLUSTERS + 1
static constexpr int HF_ = 3072;

__device__ __forceinline__ float wave_sum(float v){
#pragma unroll
  for(int o=32;o;o>>=1) v += __shfl_down(v,o);
  return v;
}

// ---------------- LayerNorm (row = 768, block = 256) ----------------
__global__ __launch_bounds__(256) void ln_kernel(const float* __restrict__ in,
    const float* __restrict__ g, const float* __restrict__ bb,
    float* __restrict__ out){
  int row = blockIdx.x;
  const float* xr = in + (size_t)row*C_;
  int tid = threadIdx.x;
  float v0=xr[tid], v1=xr[tid+256], v2=xr[tid+512];
  __shared__ float sred[4];
  __shared__ float smean, svar;
  float s = wave_sum(v0+v1+v2);
  int w=tid>>6, l=tid&63;
  if(l==0) sred[w]=s;
  __syncthreads();
  if(tid==0) smean = (sred[0]+sred[1]+sred[2]+sred[3])/(float)C_;
  __syncthreads();
  float m = smean;
  float d0=v0-m, d1=v1-m, d2=v2-m;
  float q = wave_sum(d0*d0+d1*d1+d2*d2);
  if(l==0) sred[w]=q;
  __syncthreads();
  if(tid==0) svar = (sred[0]+sred[1]+sred[2]+sred[3])/(float)C_;
  __syncthreads();
  float sq = sqrtf(svar + 1e-5f);
  float* orow = out + (size_t)row*C_;
  orow[tid]     = d0/sq*g[tid]     + bb[tid];
  orow[tid+256] = d1/sq*g[tid+256] + bb[tid+256];
  orow[tid+512] = d2/sq*g[tid+512] + bb[tid+512];
}

// ---------------- f32 tiled GEMM: C = A[MxK] @ B[KxN] (+epilogue) ----------------
// 128x128 tile, 8x8 per thread, BK=16. k-accumulation strictly sequential ->
// bit-identical to the 64x64/BK=32 version that passed (metric path safety).
// EPI: 0 = store, 1/3 = +res +bias, 2 = +bias then exact GELU
template<int EPI>
__global__ __launch_bounds__(256) void gemm_f32(const float* __restrict__ A,
    const float* __restrict__ Bw, const float* __restrict__ bias,
    const float* __restrict__ res, float* __restrict__ Cmat,
    int M, int N, int K){
  constexpr int BM=128, BN=128, BK=16;
  __shared__ float As[BK][BM+4];
  __shared__ float Bs[BK][BN+4];
  int bn = blockIdx.x*BN, bm = blockIdx.y*BM;
  int tid = threadIdx.x;
  int tm = (tid>>4)*8, tn = (tid&15)*8;
  float acc[8][8] = {};
  for(int k0=0;k0<K;k0+=BK){
#pragma unroll
    for(int t=tid;t<BM*BK;t+=256){
      int m=t>>4, kk=t&15;
      As[kk][m] = (bm+m<M) ? A[(size_t)(bm+m)*K + k0+kk] : 0.0f;
    }
#pragma unroll
    for(int t=tid;t<BK*BN;t+=256){
      int kk=t>>7, n=t&127;
      Bs[kk][n] = Bw[(size_t)(k0+kk)*N + bn+n];
    }
    __syncthreads();
#pragma unroll
    for(int kk=0;kk<BK;kk++){
      float4 a0 = *reinterpret_cast<const float4*>(&As[kk][tm]);
      float4 a1 = *reinterpret_cast<const float4*>(&As[kk][tm+4]);
      float4 b0 = *reinterpret_cast<const float4*>(&Bs[kk][tn]);
      float4 b1 = *reinterpret_cast<const float4*>(&Bs[kk][tn+4]);
      float av[8]={a0.x,a0.y,a0.z,a0.w,a1.x,a1.y,a1.z,a1.w};
      float bv[8]={b0.x,b0.y,b0.z,b0.w,b1.x,b1.y,b1.z,b1.w};
#pragma unroll
      for(int i=0;i<8;i++)
#pragma unroll
        for(int j=0;j<8;j++) acc[i][j] += av[i]*bv[j];
    }
    __syncthreads();
  }
#pragma unroll
  for(int i=0;i<8;i++){
    int m = bm+tm+i;
    if(m>=M) continue;
#pragma unroll
    for(int j=0;j<8;j++){
      int n = bn+tn+j;
      float v = acc[i][j];
      size_t idx = (size_t)m*N + n;
      if constexpr(EPI==1 || EPI==3) v = (res[idx] + v) + bias[n];
      if constexpr(EPI==2){ v += bias[n]; v = 0.5f*v*(1.0f+erff(v*0.70710678118654752f)); }
      Cmat[idx] = v;
    }
  }
}

// ---------------- metric = mean over heads of K, then L2-normalize ----------------
__global__ __launch_bounds__(64) void metric_kernel(const float* __restrict__ qkv,
    float* __restrict__ mnorm){
  int n = blockIdx.x, b = blockIdx.y, d = threadIdx.x;
  const float* base = qkv + ((size_t)(b*N_+n))*(3*C_) + C_ + d;  // k part
  float m=0;
#pragma unroll
  for(int h=0;h<H_;h++) m += base[h*64];
  m = m / 12.0f;
  float q = m*m;
#pragma unroll
  for(int o=32;o;o>>=1) q += __shfl_xor(q,o);
  float norm = sqrtf(q);
  if(n>=1) mnorm[((size_t)b*T_ + (n-1))*64 + d] = m/norm;   // drop cls token
}

// ---------------- attention: one block per (b,h); K,V staged in LDS ----------------
__global__ __launch_bounds__(256) void attn_kernel(const float* __restrict__ qkv,
    const float* __restrict__ attn_size, float* __restrict__ xa){
  int h = blockIdx.x, b = blockIdx.y;
  __shared__ float Ks[N_][65];
  __shared__ float Vs[N_][65];
  __shared__ float lsz[N_];
  __shared__ float qs[4][64];
  __shared__ float sw[4][200];
  int tid = threadIdx.x;
  for(int t=tid;t<N_*64;t+=256){
    int n=t>>6, d=t&63;
    size_t rb = ((size_t)(b*N_+n))*(3*C_) + h*64 + d;
    Ks[n][d] = qkv[rb + C_];
    Vs[n][d] = qkv[rb + 2*C_];
  }
  for(int t=tid;t<N_;t+=256) lsz[t] = logf(attn_size[b*N_+t]);
  __syncthreads();
  int w=tid>>6, l=tid&63;
  for(int r=w;r<N_;r+=4){
    qs[w][l] = qkv[((size_t)(b*N_+r))*(3*C_) + h*64 + l];
    asm volatile("s_waitcnt lgkmcnt(0)" ::: "memory");  // wave-internal LDS visibility
    float sc[4]; float smax=-INFINITY;
#pragma unroll
    for(int s=0;s<4;s++){
      int k = l + 64*s;
      float a = -INFINITY;
      if(k<N_){
        float accq=0.0f;
        for(int d=0;d<64;d++) accq += qs[w][d]*Ks[k][d];
        a = accq*0.125f + lsz[k];     // hd^-0.5 = 0.125; + log(size)
        smax = fmaxf(smax, a);
      }
      sc[s]=a;
    }
#pragma unroll
    for(int o=32;o;o>>=1) smax = fmaxf(smax, __shfl_xor(smax,o));
    float lsum=0.0f;
#pragma unroll
    for(int s=0;s<4;s++){
      int k = l + 64*s;
      if(k<N_){ float p = expf(sc[s]-smax); sw[w][k]=p; lsum+=p; }
    }
#pragma unroll
    for(int o=32;o;o>>=1) lsum += __shfl_xor(lsum,o);
    asm volatile("s_waitcnt lgkmcnt(0)" ::: "memory");
    float acc=0.0f;
    for(int k=0;k<N_;k++) acc += sw[w][k]*Vs[k][l];
    xa[((size_t)(b*N_+r))*C_ + h*64 + l] = acc/lsum;
  }
}

// ---------------- agglomerative clustering with per-row NN cache ----------------
// rowmin[r]/rowarg[r] = min value of row r over active cols / FIRST col achieving it.
// Global argmin = lexicographic min of (rowmin[r], r): since D is exactly symmetric,
// the winning row r* has rowarg[r*] > r*, so (i=r*, j=rowarg[r*]) matches the
// reference's flat row-major argmin (incl. first-index tie-breaks).
// Incremental maintenance: only column i changes value (to nd, same for row/col by
// symmetry) and column j is removed; a row needs full rescan only if its cached
// argmin was at i or j and the new value is larger.
__global__ __launch_bounds__(256) void cluster_kernel(const float* __restrict__ mnorm,
    int* __restrict__ labs_ws, float* __restrict__ labs_out){
  int b = blockIdx.x;
  __shared__ float D[T_][T_+1];          // 154,448 B
  __shared__ float sizes[T_];
  __shared__ int   labels[T_];
  __shared__ int   active[T_];
  __shared__ float rowmin[T_];
  __shared__ int   rowarg[T_];
  __shared__ int   rlist[T_];            // rescan list; reused as rank at the end
  __shared__ float rbv[4];
  __shared__ int   rbi[4];
  __shared__ int   sij[2];
  __shared__ float snn[2];
  __shared__ int   rcnt;
  int tid = threadIdx.x;
  int w = tid>>6, l = tid&63;
  const float* mb = mnorm + (size_t)b*T_*64;

  for(int t=tid;t<T_*T_;t+=256){
    int r=t/T_, c=t%T_;
    float dot=0.0f;
    for(int d=0;d<64;d++) dot += mb[r*64+d]*mb[c*64+d];
    D[r][c] = (r==c) ? INF_ : (1.0f - dot);
  }
  for(int t=tid;t<T_;t+=256){ sizes[t]=1.0f; labels[t]=t; active[t]=1; }
  __syncthreads();
  if(tid<T_){                    // init row minima (strict < -> first col)
    float bvv=INF_; int ba=0;
    for(int c=0;c<T_;c++){ float v=D[tid][c]; if(v<bvv){ bvv=v; ba=c; } }
    rowmin[tid]=bvv; rowarg[tid]=ba;
  }
  __syncthreads();

  for(int it=0; it<T_-KC_; it++){
    // --- phase A: global argmin over (rowmin[r], r) ---
    float bv = (tid<T_) ? rowmin[tid] : INF_;
    int   br = (tid<T_) ? tid : 0x7fffffff;
#pragma unroll
    for(int o=32;o;o>>=1){
      float ov=__shfl_down(bv,o); int orr=__shfl_down(br,o);
      if(ov<bv || (ov==bv && orr<br)){ bv=ov; br=orr; }
    }
    if(l==0){ rbv[w]=bv; rbi[w]=br; }
    __syncthreads();
    if(tid==0){
      bv=rbv[0]; br=rbi[0];
      for(int u=1;u<4;u++) if(rbv[u]<bv || (rbv[u]==bv && rbi[u]<br)){ bv=rbv[u]; br=rbi[u]; }
      int i=br, j=rowarg[br];
      sij[0]=i; sij[1]=j; snn[0]=sizes[i]; snn[1]=sizes[j];
      rcnt=0;
    }
    __syncthreads();
    int i=sij[0], j=sij[1]; float ni=snn[0], nj=snn[1];
    // --- phase C: read old state, compute Lance-Williams value ---
    int k=tid;
    float nd=INF_, oldrm=0.0f; int oldarg=-1; bool kact=false;
    if(k<T_){
      float di=D[i][k], dj=D[j][k];
      oldrm=rowmin[k]; oldarg=rowarg[k];
      kact = (k!=i) && (k!=j) && (active[k]!=0);
      if(kact) nd = (ni*di + nj*dj) / (ni+nj);   // same expr as passing version
    }
    __syncthreads();
    // --- phase D: write D, labels, incremental rowmin ---
    if(k<T_){
      D[i][k]=nd; D[k][i]=nd; D[j][k]=INF_; D[k][j]=INF_;
      if(labels[k]==j) labels[k]=i;
      if(k==i){
        int p=atomicAdd(&rcnt,1); rlist[p]=k;                 // row i: full rescan
      } else if(k==j){
        rowmin[k]=INF_; rowarg[k]=0;                          // deactivated
      } else if(kact){
        if(oldarg==i){
          if(nd<=oldrm) rowmin[k]=nd;                         // still first at col i
          else { int p=atomicAdd(&rcnt,1); rlist[p]=k; }
        } else if(oldarg==j){
          if(nd<=oldrm){ rowmin[k]=nd; rowarg[k]=i; }         // i<j -> first achiever
          else { int p=atomicAdd(&rcnt,1); rlist[p]=k; }
        } else {
          if(nd<oldrm || (nd==oldrm && i<oldarg)){ rowmin[k]=nd; rowarg[k]=i; }
        }
      }
    }
    if(tid==0){ sizes[i]=ni+nj; active[j]=0; }
    __syncthreads();
    // --- phase E: full rescans (one wave per flagged row) ---
    int nr = rcnt;
    for(int q=w; q<nr; q+=4){
      int rr = rlist[q];
      float v=INF_; int c=0x7fffffff;
      for(int cc=l; cc<T_; cc+=64){
        float vv=D[rr][cc];
        if(vv<v || (vv==v && cc<c)){ v=vv; c=cc; }
      }
#pragma unroll
      for(int o=32;o;o>>=1){
        float ov=__shfl_xor(v,o); int oc=__shfl_xor(c,o);
        if(ov<v || (ov==v && oc<c)){ v=ov; c=oc; }
      }
      if(l==0){ rowmin[rr]=v; rowarg[rr]=c; }
    }
    __syncthreads();
  }

  if(tid==0){
    int c=0;
    for(int t=0;t<T_;t++){ c += active[t]; rlist[t]=c-1; }   // rlist = rank now
    labs_ws[b*N_]=0; labs_out[b*N_]=0.0f;
  }
  __syncthreads();
  for(int t=tid;t<T_;t+=256){
    int lab = rlist[labels[t]] + 1;
    labs_ws[b*N_+1+t] = lab;
    labs_out[b*N_+1+t] = (float)lab;
  }
}

// ---------------- weighted-average merge: one block per (k,b) ----------------
__global__ __launch_bounds__(256) void merge_kernel(const float* __restrict__ x1,
    const float* __restrict__ asz, const int* __restrict__ labs,
    float* __restrict__ x2, float* __restrict__ size_out){
  int k = blockIdx.x, b = blockIdx.y;
  __shared__ int   lab[N_];
  __shared__ float sz[N_];
  __shared__ float ssum_s;
  int tid = threadIdx.x;
  for(int t=tid;t<N_;t+=256){ lab[t]=labs[b*N_+t]; sz[t]=asz[b*N_+t]; }
  __syncthreads();
  if(tid==0){
    float s=0.0f;
    for(int n=0;n<N_;n++) if(lab[n]==k) s += sz[n];
    ssum_s = s;
  }
  __syncthreads();
  float ssum = ssum_s;
  for(int c=tid;c<C_;c+=256){
    float acc=0.0f;
    for(int n=0;n<N_;n++) if(lab[n]==k) acc += x1[((size_t)(b*N_+n))*C_+c]*sz[n];
    x2[((size_t)(b*KT_+k))*C_+c] = acc/ssum;
  }
  if(tid==0) size_out[b*KT_+k] = ssum;
}

extern "C" void kernel_launch(void* const* d_in, const int* in_sizes, int n_in,
                              void* d_out, int out_size, void* d_ws, size_t ws_size,
                              hipStream_t stream){
  const float* x      = (const float*)d_in[0];
  const float* asz    = (const float*)d_in[1];
  const float* n1_g   = (const float*)d_in[2];
  const float* n1_b   = (const float*)d_in[3];
  const float* w_qkv  = (const float*)d_in[4];
  const float* w_proj = (const float*)d_in[5];
  const float* b_proj = (const float*)d_in[6];
  const float* n2_g   = (const float*)d_in[7];
  const float* n2_b   = (const float*)d_in[8];
  const float* w_fc1  = (const float*)d_in[9];
  const float* b_fc1  = (const float*)d_in[10];
  const float* w_fc2  = (const float*)d_in[11];
  const float* b_fc2  = (const float*)d_in[12];

  const size_t ROWS = (size_t)B_*N_;   // 12608
  float* ws   = (float*)d_ws;
  float* h    = ws;                                // [ROWS*C]   LN1 out, later x1
  float* qkv  = h + ROWS*C_;                       // [ROWS*3C]
  float* x2   = qkv;                               // reuse after qkv dead
  float* h2   = x2 + (size_t)B_*KT_*C_;            // LN2 out
  float* h3   = h2 + (size_t)B_*KT_*C_;            // fc1 out (spills into dead mnorm)
  float* mnorm= qkv + ROWS*3*C_;                   // [B*T*64]
  float* xa   = mnorm + (size_t)B_*T_*64;          // [ROWS*C]
  float* x1   = h;                                 // proj out (h dead by then)
  int*   labs = (int*)(xa + ROWS*C_);              // [B*N]

  float* out     = (float*)d_out;
  float* out_sz  = out + (size_t)B_*KT_*C_;
  float* out_lab = out_sz + (size_t)B_*KT_;

  ln_kernel<<<dim3((unsigned)ROWS),256,0,stream>>>(x, n1_g, n1_b, h);
  gemm_f32<0><<<dim3(18,99),256,0,stream>>>(h, w_qkv, nullptr, nullptr, qkv, 12608, 3*C_, C_);
  metric_kernel<<<dim3(N_,B_),64,0,stream>>>(qkv, mnorm);
  attn_kernel<<<dim3(H_,B_),256,0,stream>>>(qkv, asz, xa);
  gemm_f32<1><<<dim3(6,99),256,0,stream>>>(xa, w_proj, b_proj, x, x1, 12608, C_, C_);
  cluster_kernel<<<dim3(B_),256,0,stream>>>(mnorm, labs, out_lab);
  merge_kernel<<<dim3(KT_,B_),256,0,stream>>>(x1, asz, labs, x2, out_sz);
  ln_kernel<<<dim3((unsigned)(B_*KT_)),256,0,stream>>>(x2, n2_g, n2_b, h2);
  gemm_f32<2><<<dim3(24,50),256,0,stream>>>(h2, w_fc1, b_fc1, nullptr, h3, B_*KT_, HF_, C_);
  gemm_f32<3><<<dim3(6,50),256,0,stream>>>(h3, w_fc2, b_fc2, x2, out, B_*KT_, C_, HF_);
}

// Round 3
// 2412.602 us; speedup vs baseline: 2.4870x; 2.2429x over previous
//
#include <hip/hip_runtime.h>
#include <hip/hip_bf16.h>
#include <math.h>

#define INF_ 1e10f

static constexpr int B_  = 64;
static constexpr int N_  = 197;
static constexpr int C_  = 768;
static constexpr int H_  = 12;
static constexpr int T_  = 196;   // N-1 tokens clustered
static constexpr int KC_ = 98;    // NUM_CLUSTERS
static constexpr int KT_ = 99;    // NUM_CLUSTERS + 1
static constexpr int HF_ = 3072;

typedef __attribute__((ext_vector_type(8))) short short8v;
typedef __attribute__((ext_vector_type(4))) float f32x4;
typedef __attribute__((ext_vector_type(4))) int int4v;

__device__ __forceinline__ float wave_sum(float v){
#pragma unroll
  for(int o=32;o;o>>=1) v += __shfl_down(v,o);
  return v;
}

// ---------------- LayerNorm (row = 768, block = 256); writes f32 and/or bf16 ----------------
__global__ __launch_bounds__(256) void ln_kernel(const float* __restrict__ in,
    const float* __restrict__ g, const float* __restrict__ bb,
    float* __restrict__ outf, __hip_bfloat16* __restrict__ outb){
  int row = blockIdx.x;
  const float* xr = in + (size_t)row*C_;
  int tid = threadIdx.x;
  float v0=xr[tid], v1=xr[tid+256], v2=xr[tid+512];
  __shared__ float sred[4];
  __shared__ float smean, svar;
  float s = wave_sum(v0+v1+v2);
  int w=tid>>6, l=tid&63;
  if(l==0) sred[w]=s;
  __syncthreads();
  if(tid==0) smean = (sred[0]+sred[1]+sred[2]+sred[3])/(float)C_;
  __syncthreads();
  float m = smean;
  float d0=v0-m, d1=v1-m, d2=v2-m;
  float q = wave_sum(d0*d0+d1*d1+d2*d2);
  if(l==0) sred[w]=q;
  __syncthreads();
  if(tid==0) svar = (sred[0]+sred[1]+sred[2]+sred[3])/(float)C_;
  __syncthreads();
  float sq = sqrtf(svar + 1e-5f);
  float y0 = d0/sq*g[tid]     + bb[tid];
  float y1 = d1/sq*g[tid+256] + bb[tid+256];
  float y2 = d2/sq*g[tid+512] + bb[tid+512];
  if(outf){
    float* orow = outf + (size_t)row*C_;
    orow[tid]=y0; orow[tid+256]=y1; orow[tid+512]=y2;
  }
  if(outb){
    __hip_bfloat16* orow = outb + (size_t)row*C_;
    orow[tid]=__float2bfloat16(y0); orow[tid+256]=__float2bfloat16(y1); orow[tid+512]=__float2bfloat16(y2);
  }
}

// ---------------- Wm[c][d] = mean over heads of w_qkv k-columns (for metric) ----------------
__global__ __launch_bounds__(256) void wmean_kernel(const float* __restrict__ w,
    float* __restrict__ Wm){
  int t = blockIdx.x*256 + threadIdx.x;   // t = c*64+d
  if(t >= C_*64) return;
  int c = t>>6, d = t&63;
  const float* p = w + (size_t)c*(3*C_) + C_ + d;
  float s=0.f;
#pragma unroll
  for(int h=0;h<H_;h++) s += p[h*64];
  Wm[t] = s*(1.0f/12.0f);
}

// ---------------- transpose f32 [K,N] -> bf16 [N,K] ----------------
__global__ __launch_bounds__(256) void transpose_bf16(const float* __restrict__ w,
    __hip_bfloat16* __restrict__ wt, int K, int N){
  __shared__ float tile[32][33];
  int n0 = blockIdx.x*32, k0 = blockIdx.y*32;
  int tx = threadIdx.x&31, ty = threadIdx.x>>5;
  for(int r=ty;r<32;r+=8) tile[r][tx] = w[(size_t)(k0+r)*N + n0+tx];
  __syncthreads();
  for(int r=ty;r<32;r+=8) wt[(size_t)(n0+r)*K + k0+tx] = __float2bfloat16(tile[tx][r]);
}

// ---------------- bf16 MFMA GEMM: C = A[MxK] @ Bt[NxK]^T, f32 accum ----------------
// 128x128 tile, 4 waves in 2x2, each wave 64x64 via 4x4 frags of 16x16x32.
// EPI: 0 = store f32; 1/3 = (res + v) + bias -> f32; 2 = v+bias, exact GELU -> bf16
template<int EPI>
__global__ __launch_bounds__(256) void gemm_bf16(const ushort* __restrict__ A,
    const ushort* __restrict__ Bt, const float* __restrict__ bias,
    const float* __restrict__ res, void* __restrict__ Cout,
    int M, int N, int K){
  constexpr int BM=128, BN=128, BK=32;
  __shared__ ushort As[BM][40];
  __shared__ ushort Bs[BN][40];
  int tid = threadIdx.x;
  int bm = blockIdx.y*BM, bn = blockIdx.x*BN;
  int w = tid>>6, l = tid&63;
  int wm = (w>>1)*64, wn = (w&1)*64;
  int lr = l&15, lc = l>>4;           // frag row/col, k-chunk
  f32x4 acc[4][4] = {};
  for(int k0=0;k0<K;k0+=BK){
#pragma unroll
    for(int s=0;s<2;s++){
      int cid = tid + s*256;          // 512 chunks: row=cid>>2, ch=cid&3
      int r = cid>>2, ch = cid&3;
      int4v va = {0,0,0,0};
      if(bm+r < M) va = *reinterpret_cast<const int4v*>(A + (size_t)(bm+r)*K + k0 + ch*8);
      *reinterpret_cast<int4v*>(&As[r][ch*8]) = va;
      int4v vb = *reinterpret_cast<const int4v*>(Bt + (size_t)(bn+r)*K + k0 + ch*8);
      *reinterpret_cast<int4v*>(&Bs[r][ch*8]) = vb;
    }
    __syncthreads();
    short8v af[4], bfr[4];
#pragma unroll
    for(int f=0; f<4; f++){
      af[f]  = *reinterpret_cast<const short8v*>(&As[wm + f*16 + lr][lc*8]);
      bfr[f] = *reinterpret_cast<const short8v*>(&Bs[wn + f*16 + lr][lc*8]);
    }
#pragma unroll
    for(int i=0;i<4;i++)
#pragma unroll
      for(int j=0;j<4;j++)
        acc[i][j] = __builtin_amdgcn_mfma_f32_16x16x32_bf16(af[i], bfr[j], acc[i][j], 0,0,0);
    __syncthreads();
  }
#pragma unroll
  for(int i=0;i<4;i++){
    int rbase = bm + wm + i*16 + lc*4;
#pragma unroll
    for(int j=0;j<4;j++){
      int col = bn + wn + j*16 + lr;
#pragma unroll
      for(int r=0;r<4;r++){
        int row = rbase + r;
        if(row >= M) continue;
        size_t idx = (size_t)row*N + col;
        float v = acc[i][j][r];
        if constexpr(EPI==0) ((float*)Cout)[idx] = v;
        if constexpr(EPI==1 || EPI==3) ((float*)Cout)[idx] = (res[idx] + v) + bias[col];
        if constexpr(EPI==2){
          v += bias[col];
          v = 0.5f*v*(1.0f+erff(v*0.70710678118654752f));
          ((__hip_bfloat16*)Cout)[idx] = __float2bfloat16(v);
        }
      }
    }
  }
}

// ---------------- metric = h @ Wm (f32, sequential k), normalize, drop cls ----------------
__global__ __launch_bounds__(64) void metric_gemm(const float* __restrict__ h,
    const float* __restrict__ Wm, float* __restrict__ mnorm){
  int row = blockIdx.x;
  int b = row / N_, n = row - b*N_;
  __shared__ float hs[C_];
  int l = threadIdx.x;
  for(int c=l;c<C_;c+=64) hs[c]=h[(size_t)row*C_+c];
  __syncthreads();
  float acc=0.f;
#pragma unroll 4
  for(int c=0;c<C_;c++) acc = fmaf(hs[c], Wm[c*64+l], acc);
  float q=acc*acc;
#pragma unroll
  for(int o=32;o;o>>=1) q += __shfl_xor(q,o);
  float nrm = sqrtf(q);
  if(n>=1) mnorm[((size_t)b*T_+(n-1))*64+l] = acc/nrm;
}

// ---------------- attention: one block per (b,h); K,V staged in LDS; bf16 out ----------------
__global__ __launch_bounds__(256) void attn_kernel(const float* __restrict__ qkv,
    const float* __restrict__ attn_size, __hip_bfloat16* __restrict__ xa){
  int h = blockIdx.x, b = blockIdx.y;
  __shared__ float Ks[N_][65];
  __shared__ float Vs[N_][65];
  __shared__ float lsz[N_];
  __shared__ float qs[4][64];
  __shared__ float sw[4][200];
  int tid = threadIdx.x;
  for(int t=tid;t<N_*64;t+=256){
    int n=t>>6, d=t&63;
    size_t rb = ((size_t)(b*N_+n))*(3*C_) + h*64 + d;
    Ks[n][d] = qkv[rb + C_];
    Vs[n][d] = qkv[rb + 2*C_];
  }
  for(int t=tid;t<N_;t+=256) lsz[t] = logf(attn_size[b*N_+t]);
  __syncthreads();
  int w=tid>>6, l=tid&63;
  for(int r=w;r<N_;r+=4){
    qs[w][l] = qkv[((size_t)(b*N_+r))*(3*C_) + h*64 + l];
    asm volatile("s_waitcnt lgkmcnt(0)" ::: "memory");  // wave-internal LDS visibility
    float sc[4]; float smax=-INFINITY;
#pragma unroll
    for(int s=0;s<4;s++){
      int k = l + 64*s;
      float a = -INFINITY;
      if(k<N_){
        float accq=0.0f;
        for(int d=0;d<64;d++) accq += qs[w][d]*Ks[k][d];
        a = accq*0.125f + lsz[k];
        smax = fmaxf(smax, a);
      }
      sc[s]=a;
    }
#pragma unroll
    for(int o=32;o;o>>=1) smax = fmaxf(smax, __shfl_xor(smax,o));
    float lsum=0.0f;
#pragma unroll
    for(int s=0;s<4;s++){
      int k = l + 64*s;
      if(k<N_){ float p = expf(sc[s]-smax); sw[w][k]=p; lsum+=p; }
    }
#pragma unroll
    for(int o=32;o;o>>=1) lsum += __shfl_xor(lsum,o);
    asm volatile("s_waitcnt lgkmcnt(0)" ::: "memory");
    float acc=0.0f;
    for(int k=0;k<N_;k++) acc += sw[w][k]*Vs[k][l];
    xa[((size_t)(b*N_+r))*C_ + h*64 + l] = __float2bfloat16(acc/lsum);
  }
}

// ---------------- agglomerative clustering with per-row NN cache ----------------
__global__ __launch_bounds__(256) void cluster_kernel(const float* __restrict__ mnorm,
    int* __restrict__ labs_ws, float* __restrict__ labs_out){
  int b = blockIdx.x;
  __shared__ float D[T_][T_+1];
  __shared__ float sizes[T_];
  __shared__ int   labels[T_];
  __shared__ int   active[T_];
  __shared__ float rowmin[T_];
  __shared__ int   rowarg[T_];
  __shared__ int   rlist[T_];
  __shared__ float rbv[4];
  __shared__ int   rbi[4];
  __shared__ int   sij[2];
  __shared__ float snn[2];
  __shared__ int   rcnt;
  int tid = threadIdx.x;
  int w = tid>>6, l = tid&63;
  const float* mb = mnorm + (size_t)b*T_*64;

  for(int t=tid;t<T_*T_;t+=256){
    int r=t/T_, c=t%T_;
    float dot=0.0f;
    for(int d=0;d<64;d++) dot += mb[r*64+d]*mb[c*64+d];
    D[r][c] = (r==c) ? INF_ : (1.0f - dot);
  }
  for(int t=tid;t<T_;t+=256){ sizes[t]=1.0f; labels[t]=t; active[t]=1; }
  __syncthreads();
  if(tid<T_){
    float bvv=INF_; int ba=0;
    for(int c=0;c<T_;c++){ float v=D[tid][c]; if(v<bvv){ bvv=v; ba=c; } }
    rowmin[tid]=bvv; rowarg[tid]=ba;
  }
  __syncthreads();

  for(int it=0; it<T_-KC_; it++){
    float bv = (tid<T_) ? rowmin[tid] : INF_;
    int   br = (tid<T_) ? tid : 0x7fffffff;
#pragma unroll
    for(int o=32;o;o>>=1){
      float ov=__shfl_down(bv,o); int orr=__shfl_down(br,o);
      if(ov<bv || (ov==bv && orr<br)){ bv=ov; br=orr; }
    }
    if(l==0){ rbv[w]=bv; rbi[w]=br; }
    __syncthreads();
    if(tid==0){
      bv=rbv[0]; br=rbi[0];
      for(int u=1;u<4;u++) if(rbv[u]<bv || (rbv[u]==bv && rbi[u]<br)){ bv=rbv[u]; br=rbi[u]; }
      int i=br, j=rowarg[br];
      sij[0]=i; sij[1]=j; snn[0]=sizes[i]; snn[1]=sizes[j];
      rcnt=0;
    }
    __syncthreads();
    int i=sij[0], j=sij[1]; float ni=snn[0], nj=snn[1];
    int k=tid;
    float nd=INF_, oldrm=0.0f; int oldarg=-1; bool kact=false;
    if(k<T_){
      float di=D[i][k], dj=D[j][k];
      oldrm=rowmin[k]; oldarg=rowarg[k];
      kact = (k!=i) && (k!=j) && (active[k]!=0);
      if(kact) nd = (ni*di + nj*dj) / (ni+nj);
    }
    __syncthreads();
    if(k<T_){
      D[i][k]=nd; D[k][i]=nd; D[j][k]=INF_; D[k][j]=INF_;
      if(labels[k]==j) labels[k]=i;
      if(k==i){
        int p=atomicAdd(&rcnt,1); rlist[p]=k;
      } else if(k==j){
        rowmin[k]=INF_; rowarg[k]=0;
      } else if(kact){
        if(oldarg==i){
          if(nd<=oldrm) rowmin[k]=nd;
          else { int p=atomicAdd(&rcnt,1); rlist[p]=k; }
        } else if(oldarg==j){
          if(nd<=oldrm){ rowmin[k]=nd; rowarg[k]=i; }
          else { int p=atomicAdd(&rcnt,1); rlist[p]=k; }
        } else {
          if(nd<oldrm || (nd==oldrm && i<oldarg)){ rowmin[k]=nd; rowarg[k]=i; }
        }
      }
    }
    if(tid==0){ sizes[i]=ni+nj; active[j]=0; }
    __syncthreads();
    int nr = rcnt;
    for(int q=w; q<nr; q+=4){
      int rr = rlist[q];
      float v=INF_; int c=0x7fffffff;
      for(int cc=l; cc<T_; cc+=64){
        float vv=D[rr][cc];
        if(vv<v || (vv==v && cc<c)){ v=vv; c=cc; }
      }
#pragma unroll
      for(int o=32;o;o>>=1){
        float ov=__shfl_xor(v,o); int oc=__shfl_xor(c,o);
        if(ov<v || (ov==v && oc<c)){ v=ov; c=oc; }
      }
      if(l==0){ rowmin[rr]=v; rowarg[rr]=c; }
    }
    __syncthreads();
  }

  if(tid==0){
    int c=0;
    for(int t=0;t<T_;t++){ c += active[t]; rlist[t]=c-1; }
    labs_ws[b*N_]=0; labs_out[b*N_]=0.0f;
  }
  __syncthreads();
  for(int t=tid;t<T_;t+=256){
    int lab = rlist[labels[t]] + 1;
    labs_ws[b*N_+1+t] = lab;
    labs_out[b*N_+1+t] = (float)lab;
  }
}

// ---------------- weighted-average merge: one block per (k,b) ----------------
__global__ __launch_bounds__(256) void merge_kernel(const float* __restrict__ x1,
    const float* __restrict__ asz, const int* __restrict__ labs,
    float* __restrict__ x2, float* __restrict__ size_out){
  int k = blockIdx.x, b = blockIdx.y;
  __shared__ int   lab[N_];
  __shared__ float sz[N_];
  __shared__ float ssum_s;
  int tid = threadIdx.x;
  for(int t=tid;t<N_;t+=256){ lab[t]=labs[b*N_+t]; sz[t]=asz[b*N_+t]; }
  __syncthreads();
  if(tid==0){
    float s=0.0f;
    for(int n=0;n<N_;n++) if(lab[n]==k) s += sz[n];
    ssum_s = s;
  }
  __syncthreads();
  float ssum = ssum_s;
  for(int c=tid;c<C_;c+=256){
    float acc=0.0f;
    for(int n=0;n<N_;n++) if(lab[n]==k) acc += x1[((size_t)(b*N_+n))*C_+c]*sz[n];
    x2[((size_t)(b*KT_+k))*C_+c] = acc/ssum;
  }
  if(tid==0) size_out[b*KT_+k] = ssum;
}

extern "C" void kernel_launch(void* const* d_in, const int* in_sizes, int n_in,
                              void* d_out, int out_size, void* d_ws, size_t ws_size,
                              hipStream_t stream){
  const float* x      = (const float*)d_in[0];
  const float* asz    = (const float*)d_in[1];
  const float* n1_g   = (const float*)d_in[2];
  const float* n1_b   = (const float*)d_in[3];
  const float* w_qkv  = (const float*)d_in[4];
  const float* w_proj = (const float*)d_in[5];
  const float* b_proj = (const float*)d_in[6];
  const float* n2_g   = (const float*)d_in[7];
  const float* n2_b   = (const float*)d_in[8];
  const float* w_fc1  = (const float*)d_in[9];
  const float* b_fc1  = (const float*)d_in[10];
  const float* w_fc2  = (const float*)d_in[11];
  const float* b_fc2  = (const float*)d_in[12];

  const size_t ROWS = (size_t)B_*N_;        // 12608
  const size_t M2   = (size_t)B_*KT_;       // 6336
  float* ws = (float*)d_ws;

  // f32 regions
  float* h     = ws;                                    // [ROWS*C] LN1 out; later x1; 9,682,944
  float* qkv   = h + ROWS*C_;                           // [ROWS*3C] 29,048,832
  float* x2    = qkv;                                   // [M2*C] alias (qkv dead after attn)
  __hip_bfloat16* h2b = (__hip_bfloat16*)(qkv + M2*C_);           // [M2*C] bf16
  __hip_bfloat16* h3b = (__hip_bfloat16*)(qkv + M2*C_ + M2*C_/2); // [M2*HF] bf16
  __hip_bfloat16* hb  = (__hip_bfloat16*)(qkv + ROWS*3*C_);       // [ROWS*C] bf16; later xa
  __hip_bfloat16* xa  = hb;
  float* mnorm = (float*)(hb) + ROWS*C_/2;              // [B*T*64]
  float* Wm    = mnorm + (size_t)B_*T_*64;              // [C*64]
  __hip_bfloat16* wqkvT = (__hip_bfloat16*)(Wm + C_*64);          // [3C*C]
  __hip_bfloat16* wprojT= (__hip_bfloat16*)((float*)wqkvT + (size_t)3*C_*C_/2);
  __hip_bfloat16* wfc1T = (__hip_bfloat16*)((float*)wprojT + (size_t)C_*C_/2);
  __hip_bfloat16* wfc2T = (__hip_bfloat16*)((float*)wfc1T + (size_t)C_*HF_/2);
  int*   labs  = (int*)((float*)wfc2T + (size_t)HF_*C_/2);
  float* x1    = h;

  float* out     = (float*)d_out;
  float* out_sz  = out + M2*C_;
  float* out_lab = out_sz + M2;

  // prep
  ln_kernel<<<dim3((unsigned)ROWS),256,0,stream>>>(x, n1_g, n1_b, h, hb);
  wmean_kernel<<<dim3(192),256,0,stream>>>(w_qkv, Wm);
  transpose_bf16<<<dim3(72,24),256,0,stream>>>(w_qkv, wqkvT, C_, 3*C_);
  transpose_bf16<<<dim3(24,24),256,0,stream>>>(w_proj, wprojT, C_, C_);
  transpose_bf16<<<dim3(96,24),256,0,stream>>>(w_fc1, wfc1T, C_, HF_);
  transpose_bf16<<<dim3(24,96),256,0,stream>>>(w_fc2, wfc2T, HF_, C_);

  // attention block
  gemm_bf16<0><<<dim3(18,99),256,0,stream>>>((const ushort*)hb, (const ushort*)wqkvT,
      nullptr, nullptr, qkv, (int)ROWS, 3*C_, C_);
  metric_gemm<<<dim3((unsigned)ROWS),64,0,stream>>>(h, Wm, mnorm);
  attn_kernel<<<dim3(H_,B_),256,0,stream>>>(qkv, asz, xa);
  gemm_bf16<1><<<dim3(6,99),256,0,stream>>>((const ushort*)xa, (const ushort*)wprojT,
      b_proj, x, x1, (int)ROWS, C_, C_);

  // clustering + merge
  cluster_kernel<<<dim3(B_),256,0,stream>>>(mnorm, labs, out_lab);
  merge_kernel<<<dim3(KT_,B_),256,0,stream>>>(x1, asz, labs, x2, out_sz);

  // MLP
  ln_kernel<<<dim3((unsigned)M2),256,0,stream>>>(x2, n2_g, n2_b, nullptr, h2b);
  gemm_bf16<2><<<dim3(24,50),256,0,stream>>>((const ushort*)h2b, (const ushort*)wfc1T,
      b_fc1, nullptr, h3b, (int)M2, HF_, C_);
  gemm_bf16<3><<<dim3(6,50),256,0,stream>>>((const ushort*)h3b, (const ushort*)wfc2T,
      b_fc2, x2, out, (int)M2, C_, HF_);
}

// Round 5
// 1406.278 us; speedup vs baseline: 4.2667x; 1.7156x over previous
//
#include <hip/hip_runtime.h>
#include <hip/hip_bf16.h>
#include <math.h>

#define INF_ 1e10f

static constexpr int B_  = 64;
static constexpr int N_  = 197;
static constexpr int C_  = 768;
static constexpr int H_  = 12;
static constexpr int T_  = 196;   // N-1 tokens clustered
static constexpr int KC_ = 98;    // NUM_CLUSTERS
static constexpr int KT_ = 99;    // NUM_CLUSTERS + 1
static constexpr int HF_ = 3072;

typedef __attribute__((ext_vector_type(8))) short short8v;
typedef __attribute__((ext_vector_type(4))) float f32x4;
typedef __attribute__((ext_vector_type(4))) int int4v;

__device__ __forceinline__ float wave_sum(float v){
#pragma unroll
  for(int o=32;o;o>>=1) v += __shfl_down(v,o);
  return v;
}

__device__ __forceinline__ ushort f2bf(float v){
  __hip_bfloat16 t = __float2bfloat16(v);
  return *reinterpret_cast<const ushort*>(&t);
}

// ---------------- LayerNorm (row = 768, block = 256); writes f32 and/or bf16 ----------------
__global__ __launch_bounds__(256) void ln_kernel(const float* __restrict__ in,
    const float* __restrict__ g, const float* __restrict__ bb,
    float* __restrict__ outf, __hip_bfloat16* __restrict__ outb){
  int row = blockIdx.x;
  const float* xr = in + (size_t)row*C_;
  int tid = threadIdx.x;
  float v0=xr[tid], v1=xr[tid+256], v2=xr[tid+512];
  __shared__ float sred[4];
  __shared__ float smean, svar;
  float s = wave_sum(v0+v1+v2);
  int w=tid>>6, l=tid&63;
  if(l==0) sred[w]=s;
  __syncthreads();
  if(tid==0) smean = (sred[0]+sred[1]+sred[2]+sred[3])/(float)C_;
  __syncthreads();
  float m = smean;
  float d0=v0-m, d1=v1-m, d2=v2-m;
  float q = wave_sum(d0*d0+d1*d1+d2*d2);
  if(l==0) sred[w]=q;
  __syncthreads();
  if(tid==0) svar = (sred[0]+sred[1]+sred[2]+sred[3])/(float)C_;
  __syncthreads();
  float sq = sqrtf(svar + 1e-5f);
  float y0 = d0/sq*g[tid]     + bb[tid];
  float y1 = d1/sq*g[tid+256] + bb[tid+256];
  float y2 = d2/sq*g[tid+512] + bb[tid+512];
  if(outf){
    float* orow = outf + (size_t)row*C_;
    orow[tid]=y0; orow[tid+256]=y1; orow[tid+512]=y2;
  }
  if(outb){
    __hip_bfloat16* orow = outb + (size_t)row*C_;
    orow[tid]=__float2bfloat16(y0); orow[tid+256]=__float2bfloat16(y1); orow[tid+512]=__float2bfloat16(y2);
  }
}

// ---------------- Wm[c][d] = mean over heads of w_qkv k-columns (for metric) ----------------
__global__ __launch_bounds__(256) void wmean_kernel(const float* __restrict__ w,
    float* __restrict__ Wm){
  int t = blockIdx.x*256 + threadIdx.x;   // t = c*64+d
  if(t >= C_*64) return;
  int c = t>>6, d = t&63;
  const float* p = w + (size_t)c*(3*C_) + C_ + d;
  float s=0.f;
#pragma unroll
  for(int h=0;h<H_;h++) s += p[h*64];
  Wm[t] = s*(1.0f/12.0f);
}

// ---------------- transpose f32 [K,N] -> bf16 [N,K] ----------------
__global__ __launch_bounds__(256) void transpose_bf16(const float* __restrict__ w,
    __hip_bfloat16* __restrict__ wt, int K, int N){
  __shared__ float tile[32][33];
  int n0 = blockIdx.x*32, k0 = blockIdx.y*32;
  int tx = threadIdx.x&31, ty = threadIdx.x>>5;
  for(int r=ty;r<32;r+=8) tile[r][tx] = w[(size_t)(k0+r)*N + n0+tx];
  __syncthreads();
  for(int r=ty;r<32;r+=8) wt[(size_t)(n0+r)*K + k0+tx] = __float2bfloat16(tile[tx][r]);
}

// ---------------- bf16 MFMA GEMM: C = A[MxK] @ Bt[NxK]^T, f32 accum ----------------
// EPI: 1/3 = (res+v)+bias -> f32; 2 = v+bias, exact GELU -> bf16; 4 = store bf16
template<int EPI>
__global__ __launch_bounds__(256) void gemm_bf16(const ushort* __restrict__ A,
    const ushort* __restrict__ Bt, const float* __restrict__ bias,
    const float* __restrict__ res, void* __restrict__ Cout,
    int M, int N, int K){
  constexpr int BM=128, BN=128, BK=32;
  __shared__ ushort As[BM][40];
  __shared__ ushort Bs[BN][40];
  int tid = threadIdx.x;
  int bm = blockIdx.y*BM, bn = blockIdx.x*BN;
  int w = tid>>6, l = tid&63;
  int wm = (w>>1)*64, wn = (w&1)*64;
  int lr = l&15, lc = l>>4;           // frag row/col, k-chunk
  f32x4 acc[4][4] = {};
  for(int k0=0;k0<K;k0+=BK){
#pragma unroll
    for(int s=0;s<2;s++){
      int cid = tid + s*256;          // 512 chunks: row=cid>>2, ch=cid&3
      int r = cid>>2, ch = cid&3;
      int4v va = {0,0,0,0};
      if(bm+r < M) va = *reinterpret_cast<const int4v*>(A + (size_t)(bm+r)*K + k0 + ch*8);
      *reinterpret_cast<int4v*>(&As[r][ch*8]) = va;
      int4v vb = *reinterpret_cast<const int4v*>(Bt + (size_t)(bn+r)*K + k0 + ch*8);
      *reinterpret_cast<int4v*>(&Bs[r][ch*8]) = vb;
    }
    __syncthreads();
    short8v af[4], bfr[4];
#pragma unroll
    for(int f=0; f<4; f++){
      af[f]  = *reinterpret_cast<const short8v*>(&As[wm + f*16 + lr][lc*8]);
      bfr[f] = *reinterpret_cast<const short8v*>(&Bs[wn + f*16 + lr][lc*8]);
    }
#pragma unroll
    for(int i=0;i<4;i++)
#pragma unroll
      for(int j=0;j<4;j++)
        acc[i][j] = __builtin_amdgcn_mfma_f32_16x16x32_bf16(af[i], bfr[j], acc[i][j], 0,0,0);
    __syncthreads();
  }
#pragma unroll
  for(int i=0;i<4;i++){
    int rbase = bm + wm + i*16 + lc*4;
#pragma unroll
    for(int j=0;j<4;j++){
      int col = bn + wn + j*16 + lr;
#pragma unroll
      for(int r=0;r<4;r++){
        int row = rbase + r;
        if(row >= M) continue;
        size_t idx = (size_t)row*N + col;
        float v = acc[i][j][r];
        if constexpr(EPI==1 || EPI==3) ((float*)Cout)[idx] = (res[idx] + v) + bias[col];
        if constexpr(EPI==2){
          v += bias[col];
          v = 0.5f*v*(1.0f+erff(v*0.70710678118654752f));
          ((__hip_bfloat16*)Cout)[idx] = __float2bfloat16(v);
        }
        if constexpr(EPI==4) ((__hip_bfloat16*)Cout)[idx] = __float2bfloat16(v);
      }
    }
  }
}

// ---------------- metric = h @ Wm (f32, sequential k), normalize, drop cls ----------------
__global__ __launch_bounds__(64) void metric_gemm(const float* __restrict__ h,
    const float* __restrict__ Wm, float* __restrict__ mnorm){
  int row = blockIdx.x;
  int b = row / N_, n = row - b*N_;
  __shared__ float hs[C_];
  int l = threadIdx.x;
  for(int c=l;c<C_;c+=64) hs[c]=h[(size_t)row*C_+c];
  __syncthreads();
  float acc=0.f;
#pragma unroll 4
  for(int c=0;c<C_;c++) acc = fmaf(hs[c], Wm[c*64+l], acc);
  float q=acc*acc;
#pragma unroll
  for(int o=32;o;o>>=1) q += __shfl_xor(q,o);
  float nrm = sqrtf(q);
  if(n>=1) mnorm[((size_t)b*T_+(n-1))*64+l] = acc/nrm;
}

// ---------------- MFMA attention: one block per (b,h), 4 waves, q-tiles of 16 ----------------
// qkv is bf16 [B*N][2304]. S=197 padded to 208 (13 tiles). K in LDS [208][72],
// V^T in LDS [64][232], per-wave P [16][232] (pitches -> conflict-free b128 reads).
__global__ __launch_bounds__(256) void attn_mfma(const ushort* __restrict__ qkv,
    const float* __restrict__ attn_size, __hip_bfloat16* __restrict__ xa){
  int h = blockIdx.x, b = blockIdx.y;
  __shared__ ushort Ks[208][72];
  __shared__ ushort VsT[64][232];
  __shared__ ushort Ps[4][16][232];
  __shared__ float lsz[208];
  int tid = threadIdx.x;
  int w = tid>>6, l = tid&63;
  int lr = l&15, lc = l>>4;
  const size_t QROW = 3*C_;
  // stage K rows (zero-fill >=197)
  for(int t=tid; t<208*64; t+=256){
    int n=t>>6, d=t&63;
    ushort v = 0;
    if(n<197) v = qkv[((size_t)(b*N_+n))*QROW + C_ + h*64 + d];
    Ks[n][d] = v;
  }
  // stage V^T (zero-fill cols >=197; cols up to 231 zeroed)
  for(int t=tid; t<232*64; t+=256){
    int n=t>>6, d=t&63;
    ushort v = 0;
    if(n<197) v = qkv[((size_t)(b*N_+n))*QROW + 2*C_ + h*64 + d];
    VsT[d][n] = v;
  }
  for(int t=tid;t<208;t+=256) lsz[t] = (t<197)? logf(attn_size[b*N_+t]) : 0.f;
  // zero P pad cols 208..231 (per wave)
  for(int c=l; c<16*24; c+=64){ int rr=c/24, cc=208+(c%24); Ps[w][rr][cc]=0; }
  __syncthreads();

  for(int qt=w; qt<13; qt+=4){
    // Q A-frags straight from global bf16 (row clamped; rows>=197 not stored)
    int qrow = min(qt*16 + lr, 196);
    const ushort* qp = qkv + ((size_t)(b*N_+qrow))*QROW + h*64;
    short8v aq0 = *reinterpret_cast<const short8v*>(qp + lc*8);
    short8v aq1 = *reinterpret_cast<const short8v*>(qp + 32 + lc*8);
    // QK^T: 13 key tiles x 2 k-steps
    float sc[13][4];
#pragma unroll
    for(int t=0;t<13;t++){
      short8v b0 = *reinterpret_cast<const short8v*>(&Ks[t*16+lr][lc*8]);
      short8v b1 = *reinterpret_cast<const short8v*>(&Ks[t*16+lr][32+lc*8]);
      f32x4 a = {0.f,0.f,0.f,0.f};
      a = __builtin_amdgcn_mfma_f32_16x16x32_bf16(aq0, b0, a, 0,0,0);
      a = __builtin_amdgcn_mfma_f32_16x16x32_bf16(aq1, b1, a, 0,0,0);
      float ls = lsz[t*16+lr];
      bool mask = (t==12) && (lr>=5);
#pragma unroll
      for(int r=0;r<4;r++) sc[t][r] = mask ? -1e30f : (a[r]*0.125f + ls);
    }
    // softmax per query row (row = lc*4+r, spread over 16 lanes of same lc group)
    float rsum[4];
#pragma unroll
    for(int r=0;r<4;r++){
      float m=-1e30f;
#pragma unroll
      for(int t=0;t<13;t++) m = fmaxf(m, sc[t][r]);
#pragma unroll
      for(int o=1;o<16;o<<=1) m = fmaxf(m, __shfl_xor(m,o));
      float s=0.f;
#pragma unroll
      for(int t=0;t<13;t++){ float p=expf(sc[t][r]-m); sc[t][r]=p; s+=p; }
#pragma unroll
      for(int o=1;o<16;o<<=1) s += __shfl_xor(s,o);
      rsum[r]=s;
    }
    // store unnormalized P (bf16) into per-wave LDS
#pragma unroll
    for(int t=0;t<13;t++)
#pragma unroll
      for(int r=0;r<4;r++)
        Ps[w][lc*4+r][t*16+lr] = f2bf(sc[t][r]);
    asm volatile("s_waitcnt lgkmcnt(0)" ::: "memory");
    // PV: A = P [16 q][208 k], B^T = V^T [64 d][208 k]; 7 k-steps of 32 (pad zeroed)
    short8v ap[7];
#pragma unroll
    for(int ks=0;ks<7;ks++) ap[ks] = *reinterpret_cast<const short8v*>(&Ps[w][lr][ks*32 + lc*8]);
#pragma unroll
    for(int f=0; f<4; f++){
      f32x4 o = {0.f,0.f,0.f,0.f};
#pragma unroll
      for(int ks=0;ks<7;ks++){
        short8v bv = *reinterpret_cast<const short8v*>(&VsT[f*16+lr][ks*32 + lc*8]);
        o = __builtin_amdgcn_mfma_f32_16x16x32_bf16(ap[ks], bv, o, 0,0,0);
      }
#pragma unroll
      for(int r=0;r<4;r++){
        int q = qt*16 + lc*4 + r;
        if(q<197) xa[((size_t)(b*N_+q))*C_ + h*64 + f*16 + lr] = __float2bfloat16(o[r]/rsum[r]);
      }
    }
  }
}

// ---------------- agglomerative clustering with per-row NN cache ----------------
__global__ __launch_bounds__(256) void cluster_kernel(const float* __restrict__ mnorm,
    int* __restrict__ labs_ws, float* __restrict__ labs_out){
  int b = blockIdx.x;
  __shared__ float D[T_][T_+1];
  __shared__ float sizes[T_];
  __shared__ int   labels[T_];
  __shared__ int   active[T_];
  __shared__ float rowmin[T_];
  __shared__ int   rowarg[T_];
  __shared__ int   rlist[T_];
  __shared__ float rbv[4];
  __shared__ int   rbi[4];
  __shared__ int   sij[2];
  __shared__ float snn[2];
  __shared__ int   rcnt;
  int tid = threadIdx.x;
  int w = tid>>6, l = tid&63;
  const float* mb = mnorm + (size_t)b*T_*64;

  for(int t=tid;t<T_*T_;t+=256){
    int r=t/T_, c=t%T_;
    float dot=0.0f;
    for(int d=0;d<64;d++) dot += mb[r*64+d]*mb[c*64+d];
    D[r][c] = (r==c) ? INF_ : (1.0f - dot);
  }
  for(int t=tid;t<T_;t+=256){ sizes[t]=1.0f; labels[t]=t; active[t]=1; }
  __syncthreads();
  if(tid<T_){
    float bvv=INF_; int ba=0;
    for(int c=0;c<T_;c++){ float v=D[tid][c]; if(v<bvv){ bvv=v; ba=c; } }
    rowmin[tid]=bvv; rowarg[tid]=ba;
  }
  __syncthreads();

  for(int it=0; it<T_-KC_; it++){
    float bv = (tid<T_) ? rowmin[tid] : INF_;
    int   br = (tid<T_) ? tid : 0x7fffffff;
#pragma unroll
    for(int o=32;o;o>>=1){
      float ov=__shfl_down(bv,o); int orr=__shfl_down(br,o);
      if(ov<bv || (ov==bv && orr<br)){ bv=ov; br=orr; }
    }
    if(l==0){ rbv[w]=bv; rbi[w]=br; }
    __syncthreads();
    if(tid==0){
      bv=rbv[0]; br=rbi[0];
      for(int u=1;u<4;u++) if(rbv[u]<bv || (rbv[u]==bv && rbi[u]<br)){ bv=rbv[u]; br=rbi[u]; }
      int i=br, j=rowarg[br];
      sij[0]=i; sij[1]=j; snn[0]=sizes[i]; snn[1]=sizes[j];
      rcnt=0;
    }
    __syncthreads();
    int i=sij[0], j=sij[1]; float ni=snn[0], nj=snn[1];
    int k=tid;
    float nd=INF_, oldrm=0.0f; int oldarg=-1; bool kact=false;
    if(k<T_){
      float di=D[i][k], dj=D[j][k];
      oldrm=rowmin[k]; oldarg=rowarg[k];
      kact = (k!=i) && (k!=j) && (active[k]!=0);
      if(kact) nd = (ni*di + nj*dj) / (ni+nj);
    }
    __syncthreads();
    if(k<T_){
      D[i][k]=nd; D[k][i]=nd; D[j][k]=INF_; D[k][j]=INF_;
      if(labels[k]==j) labels[k]=i;
      if(k==i){
        int p=atomicAdd(&rcnt,1); rlist[p]=k;
      } else if(k==j){
        rowmin[k]=INF_; rowarg[k]=0;
      } else if(kact){
        if(oldarg==i){
          if(nd<=oldrm) rowmin[k]=nd;
          else { int p=atomicAdd(&rcnt,1); rlist[p]=k; }
        } else if(oldarg==j){
          if(nd<=oldrm){ rowmin[k]=nd; rowarg[k]=i; }
          else { int p=atomicAdd(&rcnt,1); rlist[p]=k; }
        } else {
          if(nd<oldrm || (nd==oldrm && i<oldarg)){ rowmin[k]=nd; rowarg[k]=i; }
        }
      }
    }
    if(tid==0){ sizes[i]=ni+nj; active[j]=0; }
    __syncthreads();
    int nr = rcnt;
    for(int q=w; q<nr; q+=4){
      int rr = rlist[q];
      float v=INF_; int c=0x7fffffff;
      for(int cc=l; cc<T_; cc+=64){
        float vv=D[rr][cc];
        if(vv<v || (vv==v && cc<c)){ v=vv; c=cc; }
      }
#pragma unroll
      for(int o=32;o;o>>=1){
        float ov=__shfl_xor(v,o); int oc=__shfl_xor(c,o);
        if(ov<v || (ov==v && oc<c)){ v=ov; c=oc; }
      }
      if(l==0){ rowmin[rr]=v; rowarg[rr]=c; }
    }
    __syncthreads();
  }

  if(tid==0){
    int c=0;
    for(int t=0;t<T_;t++){ c += active[t]; rlist[t]=c-1; }
    labs_ws[b*N_]=0; labs_out[b*N_]=0.0f;
  }
  __syncthreads();
  for(int t=tid;t<T_;t+=256){
    int lab = rlist[labels[t]] + 1;
    labs_ws[b*N_+1+t] = lab;
    labs_out[b*N_+1+t] = (float)lab;
  }
}

// ---------------- weighted-average merge: one block per (k,b) ----------------
__global__ __launch_bounds__(256) void merge_kernel(const float* __restrict__ x1,
    const float* __restrict__ asz, const int* __restrict__ labs,
    float* __restrict__ x2, float* __restrict__ size_out){
  int k = blockIdx.x, b = blockIdx.y;
  __shared__ int   lab[N_];
  __shared__ float sz[N_];
  __shared__ float ssum_s;
  int tid = threadIdx.x;
  for(int t=tid;t<N_;t+=256){ lab[t]=labs[b*N_+t]; sz[t]=asz[b*N_+t]; }
  __syncthreads();
  if(tid==0){
    float s=0.0f;
    for(int n=0;n<N_;n++) if(lab[n]==k) s += sz[n];
    ssum_s = s;
  }
  __syncthreads();
  float ssum = ssum_s;
  for(int c=tid;c<C_;c+=256){
    float acc=0.0f;
    for(int n=0;n<N_;n++) if(lab[n]==k) acc += x1[((size_t)(b*N_+n))*C_+c]*sz[n];
    x2[((size_t)(b*KT_+k))*C_+c] = acc/ssum;
  }
  if(tid==0) size_out[b*KT_+k] = ssum;
}

extern "C" void kernel_launch(void* const* d_in, const int* in_sizes, int n_in,
                              void* d_out, int out_size, void* d_ws, size_t ws_size,
                              hipStream_t stream){
  const float* x      = (const float*)d_in[0];
  const float* asz    = (const float*)d_in[1];
  const float* n1_g   = (const float*)d_in[2];
  const float* n1_b   = (const float*)d_in[3];
  const float* w_qkv  = (const float*)d_in[4];
  const float* w_proj = (const float*)d_in[5];
  const float* b_proj = (const float*)d_in[6];
  const float* n2_g   = (const float*)d_in[7];
  const float* n2_b   = (const float*)d_in[8];
  const float* w_fc1  = (const float*)d_in[9];
  const float* b_fc1  = (const float*)d_in[10];
  const float* w_fc2  = (const float*)d_in[11];
  const float* b_fc2  = (const float*)d_in[12];

  const size_t ROWS = (size_t)B_*N_;        // 12608
  const size_t M2   = (size_t)B_*KT_;       // 6336
  float* ws = (float*)d_ws;

  float* h     = ws;                                    // [ROWS*C] f32 LN1 out; later x1
  float* qkvR  = h + ROWS*C_;                           // region, ROWS*3C floats
  __hip_bfloat16* qkvb = (__hip_bfloat16*)qkvR;         // qkv as bf16 (attn-only consumer)
  float* x2    = qkvR;                                  // [M2*C] alias (qkv dead by merge)
  __hip_bfloat16* h2b = (__hip_bfloat16*)(qkvR + M2*C_);
  __hip_bfloat16* h3b = (__hip_bfloat16*)(qkvR + M2*C_ + M2*C_/2);
  __hip_bfloat16* hb  = (__hip_bfloat16*)(qkvR + ROWS*3*C_);      // [ROWS*C] bf16; later xa
  __hip_bfloat16* xa  = hb;
  float* mnorm = (float*)(hb) + ROWS*C_/2;
  float* Wm    = mnorm + (size_t)B_*T_*64;
  __hip_bfloat16* wqkvT = (__hip_bfloat16*)(Wm + C_*64);
  __hip_bfloat16* wprojT= (__hip_bfloat16*)((float*)wqkvT + (size_t)3*C_*C_/2);
  __hip_bfloat16* wfc1T = (__hip_bfloat16*)((float*)wprojT + (size_t)C_*C_/2);
  __hip_bfloat16* wfc2T = (__hip_bfloat16*)((float*)wfc1T + (size_t)C_*HF_/2);
  int*   labs  = (int*)((float*)wfc2T + (size_t)HF_*C_/2);
  float* x1    = h;

  float* out     = (float*)d_out;
  float* out_sz  = out + M2*C_;
  float* out_lab = out_sz + M2;

  // prep
  ln_kernel<<<dim3((unsigned)ROWS),256,0,stream>>>(x, n1_g, n1_b, h, hb);
  wmean_kernel<<<dim3(192),256,0,stream>>>(w_qkv, Wm);
  transpose_bf16<<<dim3(72,24),256,0,stream>>>(w_qkv, wqkvT, C_, 3*C_);
  transpose_bf16<<<dim3(24,24),256,0,stream>>>(w_proj, wprojT, C_, C_);
  transpose_bf16<<<dim3(96,24),256,0,stream>>>(w_fc1, wfc1T, C_, HF_);
  transpose_bf16<<<dim3(24,96),256,0,stream>>>(w_fc2, wfc2T, HF_, C_);

  // attention block
  gemm_bf16<4><<<dim3(18,99),256,0,stream>>>((const ushort*)hb, (const ushort*)wqkvT,
      nullptr, nullptr, qkvb, (int)ROWS, 3*C_, C_);
  metric_gemm<<<dim3((unsigned)ROWS),64,0,stream>>>(h, Wm, mnorm);
  attn_mfma<<<dim3(H_,B_),256,0,stream>>>((const ushort*)qkvb, asz, xa);
  gemm_bf16<1><<<dim3(6,99),256,0,stream>>>((const ushort*)xa, (const ushort*)wprojT,
      b_proj, x, x1, (int)ROWS, C_, C_);

  // clustering + merge
  cluster_kernel<<<dim3(B_),256,0,stream>>>(mnorm, labs, out_lab);
  merge_kernel<<<dim3(KT_,B_),256,0,stream>>>(x1, asz, labs, x2, out_sz);

  // MLP
  ln_kernel<<<dim3((unsigned)M2),256,0,stream>>>(x2, n2_g, n2_b, nullptr, h2b);
  gemm_bf16<2><<<dim3(24,50),256,0,stream>>>((const ushort*)h2b, (const ushort*)wfc1T,
      b_fc1, nullptr, h3b, (int)M2, HF_, C_);
  gemm_bf16<3><<<dim3(6,50),256,0,stream>>>((const ushort*)h3b, (const ushort*)wfc2T,
      b_fc2, x2, out, (int)M2, C_, HF_);
}